// Round 13
// baseline (186.073 us; speedup 1.0000x reference)
//
#include <hip/hip_runtime.h>
#include <cstdint>
#include <cstddef>

#define S_LEN 2048
#define DIN   512
#define DOUT  64
#define NB    4
#define NH    8

typedef __attribute__((ext_vector_type(8))) short bf16x8;
typedef __attribute__((ext_vector_type(8))) _Float16 f16x8;
typedef __attribute__((ext_vector_type(4))) float f32x4;
typedef __attribute__((ext_vector_type(16))) float f32x16;

static __device__ __forceinline__ f32x4 mfma16(bf16x8 a, bf16x8 b, f32x4 c) {
    return __builtin_amdgcn_mfma_f32_16x16x32_bf16(a, b, c, 0, 0, 0);
}
static __device__ __forceinline__ f32x16 mfma32h(f16x8 a, f16x8 b, f32x16 c) {
    return __builtin_amdgcn_mfma_f32_32x32x16_f16(a, b, c, 0, 0, 0);
}

static __device__ __forceinline__ uint16_t f2bf(float x) {
    uint32_t u = __builtin_bit_cast(uint32_t, x);
    u += 0x7fffu + ((u >> 16) & 1u);
    return (uint16_t)(u >> 16);
}
static __device__ __forceinline__ float bf2f(uint16_t h) {
    uint32_t u = ((uint32_t)h) << 16;
    return __builtin_bit_cast(float, u);
}
static __device__ __forceinline__ uint32_t cvt_pk_bf16(float lo, float hi) {
    uint32_t r;
    asm("v_cvt_pk_bf16_f32 %0, %1, %2" : "=v"(r) : "v"(lo), "v"(hi));
    return r;
}
static __device__ __forceinline__ uint32_t cvt_pkrtz_f16(float lo, float hi) {
    return __builtin_bit_cast(uint32_t, __builtin_amdgcn_cvt_pkrtz(lo, hi));
}

// ---------------------------------------------------------------------------
// Kernel 1: weight prep via LDS transpose (coalesced both sides).
// ---------------------------------------------------------------------------
__global__ __launch_bounds__(256) void prep_w(
    const float* __restrict__ w, const float* __restrict__ wo,
    uint16_t* __restrict__ whiT, uint16_t* __restrict__ wloT,
    uint16_t* __restrict__ woT)
{
    __shared__ float tile[64][65];
    const int blk = blockIdx.x;
    const int t = threadIdx.x;
    const int tq = t >> 6, tr = t & 63;

    if (blk < 192) {
        const int hp = blk >> 3, i0 = (blk & 7) * 64;
        const int p = hp % 3;
        const float s = (p == 0) ? 0.18033688011112042f : 1.0f; // 0.125*log2(e)
        const float* __restrict__ src = w + (size_t)hp * (DIN * DOUT);
        #pragma unroll
        for (int r = 0; r < 16; ++r) {
            const int ir = r * 4 + tq;
            tile[ir][tr] = src[(size_t)(i0 + ir) * DOUT + tr];
        }
        __syncthreads();
        uint16_t* __restrict__ dh = whiT + (size_t)hp * (DOUT * DIN);
        uint16_t* __restrict__ dl = wloT + (size_t)hp * (DOUT * DIN);
        #pragma unroll
        for (int r = 0; r < 16; ++r) {
            const int o = r * 4 + tq;
            const float v = tile[tr][o] * s;
            const uint16_t hi = f2bf(v);
            dh[(size_t)o * DIN + i0 + tr] = hi;
            dl[(size_t)o * DIN + i0 + tr] = f2bf(v - bf2f(hi));
        }
    } else {
        const int i0 = (blk - 192) * 64;
        #pragma unroll
        for (int r = 0; r < 16; ++r) {
            const int ir = r * 4 + tq;
            tile[ir][tr] = wo[(size_t)(i0 + ir) * DOUT + tr];
        }
        __syncthreads();
        #pragma unroll
        for (int r = 0; r < 16; ++r) {
            const int o = r * 4 + tq;
            woT[(size_t)o * DIN + i0 + tr] = f2bf(tile[tr][o]);
        }
    }
}

// ---------------------------------------------------------------------------
// Kernel 2: split x [8192][512] fp32 -> xhi/xlo bf16 (vectorized, one pass).
// ---------------------------------------------------------------------------
__global__ __launch_bounds__(256) void split_x(
    const float* __restrict__ x, uint16_t* __restrict__ xhi, uint16_t* __restrict__ xlo)
{
    const size_t idx = ((size_t)blockIdx.x * 256 + threadIdx.x) * 8;
    const float4 a = *(const float4*)(x + idx);
    const float4 b = *(const float4*)(x + idx + 4);
    const float xv[8] = {a.x, a.y, a.z, a.w, b.x, b.y, b.z, b.w};
    union { uint16_t u[8]; uint4 v; } H, L;
    #pragma unroll
    for (int j = 0; j < 8; ++j) {
        const uint16_t hi = f2bf(xv[j]);
        H.u[j] = hi;
        L.u[j] = f2bf(xv[j] - bf2f(hi));
    }
    *(uint4*)(xhi + idx) = H.v;
    *(uint4*)(xlo + idx) = L.v;
}

// ---------------------------------------------------------------------------
// Kernel 3: QKV projection GEMM, fused 3-term split precision.
//   REG-STAGING (T14): global_load -> VGPR -> ds_write_b128 replaces
//   global_load_lds (which is lane-serial ~16B/cyc/CU; regular loads ~60B/cyc).
//   Same LDS layout/addresses as before. 96 MFMA per barrier-pair.
// Outputs: q,k fp16 [bh][s][64]; vT fp16 [bh][d][s] (pre-transposed).
// ---------------------------------------------------------------------------
__global__ __launch_bounds__(256, 2) void gemm_qkv(
    const uint16_t* __restrict__ xhi, const uint16_t* __restrict__ xlo,
    const uint16_t* __restrict__ whiT, const uint16_t* __restrict__ wloT,
    uint16_t* __restrict__ qf, uint16_t* __restrict__ kf,
    uint16_t* __restrict__ vT)
{
    __shared__ __align__(16) uint16_t lds[4 * 128 * 64];   // 64 KB: ah|al|bh|bl

    const int bid = blockIdx.x;
    const int xcd = bid & 7, wi = bid >> 3;
    const int mt = xcd * 8 + wi / 12, nt = wi % 12;
    const int m0 = mt * 128, n0 = nt * 128;
    const int tid = threadIdx.x;
    const int l = tid & 63, w = tid >> 6;
    const int g = l >> 4, lm = l & 15;
    const int wm = w >> 1, wn = w & 1;

    const f32x4 Z = {0.f, 0.f, 0.f, 0.f};
    f32x4 acc[4][4];
    #pragma unroll
    for (int a = 0; a < 4; ++a)
        #pragma unroll
        for (int b = 0; b < 4; ++b) acc[a][b] = Z;

    int srow[4], scol[4];
    #pragma unroll
    for (int i = 0; i < 4; ++i) {
        const int c = i * 256 + tid;
        srow[i] = c >> 3;
        scol[i] = ((c & 7) * 8) ^ ((srow[i] & 7) << 3);
    }

    for (int kt = 0; kt < 8; ++kt) {
        const int k0 = kt * 64;
        uint4 stg[16];
        #pragma unroll
        for (int i = 0; i < 4; ++i) {
            const size_t aoff = (size_t)(m0 + srow[i]) * DIN + k0 + scol[i];
            const size_t boff = (size_t)(n0 + srow[i]) * DIN + k0 + scol[i];
            stg[i * 4 + 0] = *(const uint4*)(xhi  + aoff);
            stg[i * 4 + 1] = *(const uint4*)(xlo  + aoff);
            stg[i * 4 + 2] = *(const uint4*)(whiT + boff);
            stg[i * 4 + 3] = *(const uint4*)(wloT + boff);
        }
        #pragma unroll
        for (int i = 0; i < 4; ++i) {
            const int c8 = (i * 256 + tid) * 8;
            *(uint4*)&lds[c8]                 = stg[i * 4 + 0];
            *(uint4*)&lds[128 * 64 + c8]      = stg[i * 4 + 1];
            *(uint4*)&lds[2 * 128 * 64 + c8]  = stg[i * 4 + 2];
            *(uint4*)&lds[3 * 128 * 64 + c8]  = stg[i * 4 + 3];
        }
        __syncthreads();

        bf16x8 ah[4][2], al[4][2];
        #pragma unroll
        for (int mi = 0; mi < 4; ++mi) {
            const int r = wm * 64 + mi * 16 + lm;
            const int rb = r * 128;
            #pragma unroll
            for (int kk = 0; kk < 2; ++kk) {
                const int cb = (kk * 64 + g * 16) ^ ((r & 7) << 4);
                ah[mi][kk] = *(const bf16x8*)((const char*)lds + rb + cb);
                al[mi][kk] = *(const bf16x8*)((const char*)lds + 16384 + rb + cb);
            }
        }
        #pragma unroll
        for (int ni = 0; ni < 4; ++ni) {
            const int r = wn * 64 + ni * 16 + lm;
            const int rb = r * 128;
            bf16x8 bh[2], bl[2];
            #pragma unroll
            for (int kk = 0; kk < 2; ++kk) {
                const int cb = (kk * 64 + g * 16) ^ ((r & 7) << 4);
                bh[kk] = *(const bf16x8*)((const char*)lds + 32768 + rb + cb);
                bl[kk] = *(const bf16x8*)((const char*)lds + 49152 + rb + cb);
            }
            #pragma unroll
            for (int mi = 0; mi < 4; ++mi) {
                acc[mi][ni] = mfma16(ah[mi][0], bh[0], acc[mi][ni]);
                acc[mi][ni] = mfma16(ah[mi][1], bh[1], acc[mi][ni]);
                acc[mi][ni] = mfma16(ah[mi][0], bl[0], acc[mi][ni]);
                acc[mi][ni] = mfma16(ah[mi][1], bl[1], acc[mi][ni]);
                acc[mi][ni] = mfma16(al[mi][0], bh[0], acc[mi][ni]);
                acc[mi][ni] = mfma16(al[mi][1], bh[1], acc[mi][ni]);
            }
        }
        __syncthreads();
    }

    #pragma unroll
    for (int ni = 0; ni < 4; ++ni) {
        const int n = n0 + wn * 64 + ni * 16 + lm;
        const int hp = n >> 6, o = n & 63;
        const int h = hp / 3, p = hp - h * 3;
        if (p < 2) {
            uint16_t* __restrict__ dst = (p == 0) ? qf : kf;
            #pragma unroll
            for (int mi = 0; mi < 4; ++mi) {
                #pragma unroll
                for (int j = 0; j < 4; ++j) {
                    const int m = m0 + wm * 64 + mi * 16 + 4 * g + j;
                    const int b = m >> 11, s = m & 2047;
                    const size_t idx = ((size_t)(b * NH + h) * S_LEN + s) * DOUT + o;
                    const _Float16 hv = (_Float16)acc[mi][ni][j];  // RNE
                    dst[idx] = __builtin_bit_cast(uint16_t, hv);
                }
            }
        } else {
            #pragma unroll
            for (int mi = 0; mi < 4; ++mi) {
                const int m = m0 + wm * 64 + mi * 16 + 4 * g;  // 4 consecutive s
                const int b = m >> 11, s = m & 2047;
                union { _Float16 h[4]; uint2 u; } pk;
                pk.h[0] = (_Float16)acc[mi][ni][0];
                pk.h[1] = (_Float16)acc[mi][ni][1];
                pk.h[2] = (_Float16)acc[mi][ni][2];
                pk.h[3] = (_Float16)acc[mi][ni][3];
                *(uint2*)(vT + ((size_t)((b * NH + h) * DOUT + o)) * S_LEN + s) = pk.u;
            }
        }
    }
}

// ---------------------------------------------------------------------------
// Kernel 4: flash attention, ALL-REGISTER: no LDS, no barriers, no DMA.
//   Each lane's K/V MFMA fragments are lane-local 16B global chunks:
//     K(ks,dsub): kf + base + (t*64+ks*32+lq)*64 + dsub*16 + L*8
//     V(dh,kc):   vT + base + (dh*32+lq)*2048*? ... vp + dh*65536 + t*64 + kc*16
//   2 K reg-sets (2-tile prefetch) + 1 V set; compiler emits counted vmcnt.
//   QK(kt+1) [MFMA] || softmax(kt) [VALU] pipeline retained. Softmax: local
//   tree max, max-shfl only inside rare rescale branch, per-lane l partial
//   (row sum deferred to epilogue). Siblings share tiles via L1.
// ---------------------------------------------------------------------------
__global__ __launch_bounds__(256, 2) void attn_fwd(
    const uint16_t* __restrict__ qf, const uint16_t* __restrict__ kf,
    const uint16_t* __restrict__ vT, uint16_t* __restrict__ oc)
{
    const int bid = blockIdx.x;
    const int qt = (bid >> 3) & 15, bh = (bid & 7) + 8 * (bid >> 7);
    const int tid = threadIdx.x;
    const int l = tid & 63, wq = tid >> 6;
    const int L = l >> 5, lq = l & 31;
    const size_t base = (size_t)bh * (S_LEN * DOUT);

    // Q B-fragments (fp16): lane holds Q[q = qrow][d = dsub*16 + 8L + j]
    const int qrow = qt * 128 + wq * 32 + lq;
    const uint16_t* qp = qf + base + (size_t)qrow * DOUT;
    f16x8 qv[4];
    #pragma unroll
    for (int dsub = 0; dsub < 4; ++dsub)
        qv[dsub] = *(const f16x8*)(qp + dsub * 16 + L * 8);

    // lane-fixed bases for direct fragment loads
    const uint16_t* kp = kf + base + (size_t)lq * DOUT + L * 8;
    const uint16_t* vp = vT + base + (size_t)lq * S_LEN + L * 8;

    f32x16 Zv;
    #pragma unroll
    for (int r = 0; r < 16; ++r) Zv[r] = 0.f;
    f32x16 Oa[2] = {Zv, Zv};           // O^T[d = dh*32 + row(reg,L)][q = lq]
    float m_run = -INFINITY, l_run = 0.f;   // l_run is PER-LANE partial

    f16x8 KA[8], KB[8], Vr[8];

    auto loadK = [&](f16x8* dst, int t) {
        #pragma unroll
        for (int ks = 0; ks < 2; ++ks)
            #pragma unroll
            for (int dsub = 0; dsub < 4; ++dsub)
                dst[ks * 4 + dsub] =
                    *(const f16x8*)(kp + t * 4096 + ks * 2048 + dsub * 16);
    };
    auto loadV = [&](f16x8* dst, int t) {
        #pragma unroll
        for (int dh = 0; dh < 2; ++dh)
            #pragma unroll
            for (int kc = 0; kc < 4; ++kc)
                dst[dh * 4 + kc] =
                    *(const f16x8*)(vp + dh * 65536 + t * 64 + kc * 16);
    };
    auto qk_step = [&](const f16x8* K, f32x16* dst) {
        __builtin_amdgcn_s_setprio(1);
        #pragma unroll
        for (int ks = 0; ks < 2; ++ks) {
            f32x16 s = Zv;
            #pragma unroll
            for (int dsub = 0; dsub < 4; ++dsub)
                s = mfma32h(K[ks * 4 + dsub], qv[dsub], s);
            dst[ks] = s;
        }
        __builtin_amdgcn_s_setprio(0);
    };

    // prologue: K(0)->KA, K(1)->KB, V(0)->Vr; QK(0)->saA
    loadK(KA, 0);
    loadK(KB, 1);
    loadV(Vr, 0);
    f32x16 saA[2], saB[2];
    qk_step(KA, saA);

    // iter body: sa holds scores(kt); Kuse holds K(kt+1).
    auto body = [&](int kt, f32x16* sa, f32x16* sb, const f16x8* Kuse) {
        // QK(kt+1) (MFMA) — independent of softmax(kt) below; interleaves
        qk_step(Kuse, sb);

        // softmax(kt): local tree max
        float mx[16];
        #pragma unroll
        for (int r = 0; r < 16; ++r) mx[r] = fmaxf(sa[0][r], sa[1][r]);
        #pragma unroll
        for (int st = 8; st >= 1; st >>= 1)
            #pragma unroll
            for (int r = 0; r < st; ++r) mx[r] = fmaxf(mx[r], mx[r + st]);
        const float pmax = mx[0];

        if (!__all(pmax - m_run <= 8.f)) {          // rare (defer-max)
            const float pmr = fmaxf(pmax, __shfl_xor(pmax, 32));
            const float m_new = fmaxf(m_run, pmr);
            const float alpha = __builtin_amdgcn_exp2f(m_run - m_new);
            m_run = m_new;
            #pragma unroll
            for (int r = 0; r < 16; ++r) { Oa[0][r] *= alpha; Oa[1][r] *= alpha; }
            l_run *= alpha;
        }

        #pragma unroll
        for (int ks = 0; ks < 2; ++ks)
            #pragma unroll
            for (int r = 0; r < 16; ++r)
                sa[ks][r] = __builtin_amdgcn_exp2f(sa[ks][r] - m_run);

        // local tree sum; row-combine deferred to epilogue
        float sm[16];
        #pragma unroll
        for (int r = 0; r < 16; ++r) sm[r] = sa[0][r] + sa[1][r];
        #pragma unroll
        for (int st = 8; st >= 1; st >>= 1)
            #pragma unroll
            for (int r = 0; r < st; ++r) sm[r] += sm[r + st];
        l_run += sm[0];

        // pack P (fp16) into PV B-fragments; permlane VDST = lo pack
        f16x8 pfrag[4];
        #pragma unroll
        for (int ks = 0; ks < 2; ++ks) {
            uint32_t a0 = cvt_pkrtz_f16(sa[ks][0], sa[ks][1]);
            uint32_t a1 = cvt_pkrtz_f16(sa[ks][2], sa[ks][3]);
            uint32_t a2 = cvt_pkrtz_f16(sa[ks][4], sa[ks][5]);
            uint32_t a3 = cvt_pkrtz_f16(sa[ks][6], sa[ks][7]);
            asm volatile("v_permlane32_swap_b32 %0, %1" : "+v"(a0), "+v"(a2));
            asm volatile("v_permlane32_swap_b32 %0, %1" : "+v"(a1), "+v"(a3));
            union { uint32_t w[4]; f16x8 v; } u;
            u.w[0] = a0; u.w[1] = a1; u.w[2] = a2; u.w[3] = a3;
            pfrag[2 * ks] = u.v;
            uint32_t b0 = cvt_pkrtz_f16(sa[ks][8],  sa[ks][9]);
            uint32_t b1 = cvt_pkrtz_f16(sa[ks][10], sa[ks][11]);
            uint32_t b2 = cvt_pkrtz_f16(sa[ks][12], sa[ks][13]);
            uint32_t b3 = cvt_pkrtz_f16(sa[ks][14], sa[ks][15]);
            asm volatile("v_permlane32_swap_b32 %0, %1" : "+v"(b0), "+v"(b2));
            asm volatile("v_permlane32_swap_b32 %0, %1" : "+v"(b1), "+v"(b3));
            union { uint32_t w[4]; f16x8 v; } u2;
            u2.w[0] = b0; u2.w[1] = b1; u2.w[2] = b2; u2.w[3] = b3;
            pfrag[2 * ks + 1] = u2.v;
        }

        // PV(kt) from V regs
        __builtin_amdgcn_s_setprio(1);
        #pragma unroll
        for (int dh = 0; dh < 2; ++dh)
            #pragma unroll
            for (int kc = 0; kc < 4; ++kc)
                Oa[dh] = mfma32h(Vr[dh * 4 + kc], pfrag[kc], Oa[dh]);
        __builtin_amdgcn_s_setprio(0);

        // issue V(kt+1) (WAR after PV; lands during next iter's QK+softmax)
        loadV(Vr, (kt + 1 < 32) ? kt + 1 : 0);
    };

    for (int t = 0; t < 16; ++t) {
        const int kt0 = 2 * t, kt1 = 2 * t + 1;
        loadK(KA, (kt0 + 2 < 32) ? kt0 + 2 : 0);   // K(kt0+2) -> KA (K(kt0) dead)
        body(kt0, saA, saB, KB);
        loadK(KB, (kt1 + 2 < 32) ? kt1 + 2 : 0);   // K(kt1+2) -> KB
        body(kt1, saB, saA, KA);
    }

    // epilogue: combine per-lane l partials, normalize, write oc bf16
    const float l_row = l_run + __shfl_xor(l_run, 32);
    const float li = 1.f / l_row;
    const int b = bh >> 3, hh = bh & 7;
    const int srow = qt * 128 + wq * 32 + lq;
    const size_t rbase = ((size_t)b * S_LEN + srow) * (NH * DOUT) + hh * DOUT;
    #pragma unroll
    for (int dh = 0; dh < 2; ++dh) {
        #pragma unroll
        for (int rq = 0; rq < 4; ++rq) {
            const int d0 = dh * 32 + rq * 8 + L * 4;
            uint2 val;
            val.x = cvt_pk_bf16(Oa[dh][rq * 4 + 0] * li, Oa[dh][rq * 4 + 1] * li);
            val.y = cvt_pk_bf16(Oa[dh][rq * 4 + 2] * li, Oa[dh][rq * 4 + 3] * li);
            *(uint2*)(oc + rbase + d0) = val;
        }
    }
}

// ---------------------------------------------------------------------------
// Kernel 5: output projection out = o_concat[8192x512] @ wo[512x64], fp32 out.
// ---------------------------------------------------------------------------
__global__ __launch_bounds__(256) void oproj(
    const uint16_t* __restrict__ oc, const uint16_t* __restrict__ woT,
    float* __restrict__ out)
{
    const int mt = blockIdx.x;
    const int tid = threadIdx.x;
    const int l = tid & 63, w = tid >> 6;
    const int g = l >> 4, lm = l & 15;
    const int m0 = mt * 64 + w * 16;
    const f32x4 Z = {0.f, 0.f, 0.f, 0.f};
    f32x4 acc[4] = {Z, Z, Z, Z};
    const uint16_t* __restrict__ arow = oc + (size_t)(m0 + lm) * (NH * DOUT);
    for (int kc = 0; kc < 16; ++kc) {
        const bf16x8 a = *(const bf16x8*)(arow + kc * 32 + g * 8);
        #pragma unroll
        for (int nt = 0; nt < 4; ++nt) {
            const bf16x8 bfr = *(const bf16x8*)(woT + (size_t)(nt * 16 + lm) * (NH * DOUT) + kc * 32 + g * 8);
            acc[nt] = mfma16(a, bfr, acc[nt]);
        }
    }
    #pragma unroll
    for (int nt = 0; nt < 4; ++nt)
        #pragma unroll
        for (int j = 0; j < 4; ++j)
            out[(size_t)(m0 + 4 * g + j) * DOUT + nt * 16 + lm] = acc[nt][j];
}

// ---------------------------------------------------------------------------
extern "C" void kernel_launch(void* const* d_in, const int* in_sizes, int n_in,
                              void* d_out, int out_size, void* d_ws, size_t ws_size,
                              hipStream_t stream) {
    const float* x  = (const float*)d_in[0];
    const float* w  = (const float*)d_in[1];
    const float* wo = (const float*)d_in[2];
    float* out = (float*)d_out;

    char* ws = (char*)d_ws;
    uint16_t* qf   = (uint16_t*)(ws);              // [B*H][S][64] fp16, 8 MB
    uint16_t* kf   = (uint16_t*)(ws + 8388608);    // fp16, 8 MB
    uint16_t* vT   = (uint16_t*)(ws + 16777216);   // [B*H][64][S] fp16, 8 MB
    uint16_t* xhi  = (uint16_t*)(ws + 25165824);   // bf16, 8 MB (-> oc)
    uint16_t* xlo  = (uint16_t*)(ws + 33554432);   // bf16, 8 MB
    uint16_t* whiT = (uint16_t*)(ws + 41943040);   // [1536][512] bf16
    uint16_t* wloT = (uint16_t*)(ws + 43515904);
    uint16_t* woT  = (uint16_t*)(ws + 45088768);   // 65536 B
    // oc aliases xhi (dead after gemm_qkv; split_x rewrites it every call).
    uint16_t* oc   = xhi;
    // total: 45154304 B (~43 MB)

    hipLaunchKernelGGL(prep_w, dim3(200), dim3(256), 0, stream, w, wo, whiT, wloT, woT);
    hipLaunchKernelGGL(split_x, dim3(2048), dim3(256), 0, stream, x, xhi, xlo);
    hipLaunchKernelGGL(gemm_qkv, dim3(768), dim3(256), 0, stream,
                       xhi, xlo, whiT, wloT, qf, kf, vT);
    hipLaunchKernelGGL(attn_fwd, dim3(512), dim3(256), 0, stream,
                       qf, kf, vT, oc);
    hipLaunchKernelGGL(oproj, dim3(128), dim3(256), 0, stream, oc, woT, out);
}

// Round 14
// 154.402 us; speedup vs baseline: 1.2051x; 1.2051x over previous
//
#include <hip/hip_runtime.h>
#include <cstdint>
#include <cstddef>

#define S_LEN 2048
#define DIN   512
#define DOUT  64
#define NB    4
#define NH    8

typedef __attribute__((ext_vector_type(8))) short bf16x8;
typedef __attribute__((ext_vector_type(8))) _Float16 f16x8;
typedef __attribute__((ext_vector_type(4))) float f32x4;
typedef __attribute__((ext_vector_type(16))) float f32x16;

static __device__ __forceinline__ f32x4 mfma16(bf16x8 a, bf16x8 b, f32x4 c) {
    return __builtin_amdgcn_mfma_f32_16x16x32_bf16(a, b, c, 0, 0, 0);
}
static __device__ __forceinline__ f32x16 mfma32h(f16x8 a, f16x8 b, f32x16 c) {
    return __builtin_amdgcn_mfma_f32_32x32x16_f16(a, b, c, 0, 0, 0);
}

static __device__ __forceinline__ uint16_t f2bf(float x) {
    uint32_t u = __builtin_bit_cast(uint32_t, x);
    u += 0x7fffu + ((u >> 16) & 1u);
    return (uint16_t)(u >> 16);
}
static __device__ __forceinline__ float bf2f(uint16_t h) {
    uint32_t u = ((uint32_t)h) << 16;
    return __builtin_bit_cast(float, u);
}
static __device__ __forceinline__ uint32_t cvt_pk_bf16(float lo, float hi) {
    uint32_t r;
    asm("v_cvt_pk_bf16_f32 %0, %1, %2" : "=v"(r) : "v"(lo), "v"(hi));
    return r;
}
static __device__ __forceinline__ uint32_t cvt_pkrtz_f16(float lo, float hi) {
    return __builtin_bit_cast(uint32_t, __builtin_amdgcn_cvt_pkrtz(lo, hi));
}

// ---------------------------------------------------------------------------
// Kernel 1: weight prep via LDS transpose (coalesced both sides).
// ---------------------------------------------------------------------------
__global__ __launch_bounds__(256) void prep_w(
    const float* __restrict__ w, const float* __restrict__ wo,
    uint16_t* __restrict__ whiT, uint16_t* __restrict__ wloT,
    uint16_t* __restrict__ woT)
{
    __shared__ float tile[64][65];
    const int blk = blockIdx.x;
    const int t = threadIdx.x;
    const int tq = t >> 6, tr = t & 63;

    if (blk < 192) {
        const int hp = blk >> 3, i0 = (blk & 7) * 64;
        const int p = hp % 3;
        const float s = (p == 0) ? 0.18033688011112042f : 1.0f; // 0.125*log2(e)
        const float* __restrict__ src = w + (size_t)hp * (DIN * DOUT);
        #pragma unroll
        for (int r = 0; r < 16; ++r) {
            const int ir = r * 4 + tq;
            tile[ir][tr] = src[(size_t)(i0 + ir) * DOUT + tr];
        }
        __syncthreads();
        uint16_t* __restrict__ dh = whiT + (size_t)hp * (DOUT * DIN);
        uint16_t* __restrict__ dl = wloT + (size_t)hp * (DOUT * DIN);
        #pragma unroll
        for (int r = 0; r < 16; ++r) {
            const int o = r * 4 + tq;
            const float v = tile[tr][o] * s;
            const uint16_t hi = f2bf(v);
            dh[(size_t)o * DIN + i0 + tr] = hi;
            dl[(size_t)o * DIN + i0 + tr] = f2bf(v - bf2f(hi));
        }
    } else {
        const int i0 = (blk - 192) * 64;
        #pragma unroll
        for (int r = 0; r < 16; ++r) {
            const int ir = r * 4 + tq;
            tile[ir][tr] = wo[(size_t)(i0 + ir) * DOUT + tr];
        }
        __syncthreads();
        #pragma unroll
        for (int r = 0; r < 16; ++r) {
            const int o = r * 4 + tq;
            woT[(size_t)o * DIN + i0 + tr] = f2bf(tile[tr][o]);
        }
    }
}

// ---------------------------------------------------------------------------
// Kernel 2: split x [8192][512] fp32 -> xhi/xlo bf16 (vectorized, one pass).
// ---------------------------------------------------------------------------
__global__ __launch_bounds__(256) void split_x(
    const float* __restrict__ x, uint16_t* __restrict__ xhi, uint16_t* __restrict__ xlo)
{
    const size_t idx = ((size_t)blockIdx.x * 256 + threadIdx.x) * 8;
    const float4 a = *(const float4*)(x + idx);
    const float4 b = *(const float4*)(x + idx + 4);
    const float xv[8] = {a.x, a.y, a.z, a.w, b.x, b.y, b.z, b.w};
    union { uint16_t u[8]; uint4 v; } H, L;
    #pragma unroll
    for (int j = 0; j < 8; ++j) {
        const uint16_t hi = f2bf(xv[j]);
        H.u[j] = hi;
        L.u[j] = f2bf(xv[j] - bf2f(hi));
    }
    *(uint4*)(xhi + idx) = H.v;
    *(uint4*)(xlo + idx) = L.v;
}

// ---------------------------------------------------------------------------
// Kernel 3: QKV projection GEMM, fused 3-term split precision, reg-staged
// (T14; unchanged from R13). Outputs: q,k fp16 [bh][s][64]; vT fp16 [bh][d][s].
// ---------------------------------------------------------------------------
__global__ __launch_bounds__(256, 2) void gemm_qkv(
    const uint16_t* __restrict__ xhi, const uint16_t* __restrict__ xlo,
    const uint16_t* __restrict__ whiT, const uint16_t* __restrict__ wloT,
    uint16_t* __restrict__ qf, uint16_t* __restrict__ kf,
    uint16_t* __restrict__ vT)
{
    __shared__ __align__(16) uint16_t lds[4 * 128 * 64];   // 64 KB: ah|al|bh|bl

    const int bid = blockIdx.x;
    const int xcd = bid & 7, wi = bid >> 3;
    const int mt = xcd * 8 + wi / 12, nt = wi % 12;
    const int m0 = mt * 128, n0 = nt * 128;
    const int tid = threadIdx.x;
    const int l = tid & 63, w = tid >> 6;
    const int g = l >> 4, lm = l & 15;
    const int wm = w >> 1, wn = w & 1;

    const f32x4 Z = {0.f, 0.f, 0.f, 0.f};
    f32x4 acc[4][4];
    #pragma unroll
    for (int a = 0; a < 4; ++a)
        #pragma unroll
        for (int b = 0; b < 4; ++b) acc[a][b] = Z;

    int srow[4], scol[4];
    #pragma unroll
    for (int i = 0; i < 4; ++i) {
        const int c = i * 256 + tid;
        srow[i] = c >> 3;
        scol[i] = ((c & 7) * 8) ^ ((srow[i] & 7) << 3);
    }

    for (int kt = 0; kt < 8; ++kt) {
        const int k0 = kt * 64;
        uint4 stg[16];
        #pragma unroll
        for (int i = 0; i < 4; ++i) {
            const size_t aoff = (size_t)(m0 + srow[i]) * DIN + k0 + scol[i];
            const size_t boff = (size_t)(n0 + srow[i]) * DIN + k0 + scol[i];
            stg[i * 4 + 0] = *(const uint4*)(xhi  + aoff);
            stg[i * 4 + 1] = *(const uint4*)(xlo  + aoff);
            stg[i * 4 + 2] = *(const uint4*)(whiT + boff);
            stg[i * 4 + 3] = *(const uint4*)(wloT + boff);
        }
        #pragma unroll
        for (int i = 0; i < 4; ++i) {
            const int c8 = (i * 256 + tid) * 8;
            *(uint4*)&lds[c8]                 = stg[i * 4 + 0];
            *(uint4*)&lds[128 * 64 + c8]      = stg[i * 4 + 1];
            *(uint4*)&lds[2 * 128 * 64 + c8]  = stg[i * 4 + 2];
            *(uint4*)&lds[3 * 128 * 64 + c8]  = stg[i * 4 + 3];
        }
        __syncthreads();

        bf16x8 ah[4][2], al[4][2];
        #pragma unroll
        for (int mi = 0; mi < 4; ++mi) {
            const int r = wm * 64 + mi * 16 + lm;
            const int rb = r * 128;
            #pragma unroll
            for (int kk = 0; kk < 2; ++kk) {
                const int cb = (kk * 64 + g * 16) ^ ((r & 7) << 4);
                ah[mi][kk] = *(const bf16x8*)((const char*)lds + rb + cb);
                al[mi][kk] = *(const bf16x8*)((const char*)lds + 16384 + rb + cb);
            }
        }
        #pragma unroll
        for (int ni = 0; ni < 4; ++ni) {
            const int r = wn * 64 + ni * 16 + lm;
            const int rb = r * 128;
            bf16x8 bh[2], bl[2];
            #pragma unroll
            for (int kk = 0; kk < 2; ++kk) {
                const int cb = (kk * 64 + g * 16) ^ ((r & 7) << 4);
                bh[kk] = *(const bf16x8*)((const char*)lds + 32768 + rb + cb);
                bl[kk] = *(const bf16x8*)((const char*)lds + 49152 + rb + cb);
            }
            #pragma unroll
            for (int mi = 0; mi < 4; ++mi) {
                acc[mi][ni] = mfma16(ah[mi][0], bh[0], acc[mi][ni]);
                acc[mi][ni] = mfma16(ah[mi][1], bh[1], acc[mi][ni]);
                acc[mi][ni] = mfma16(ah[mi][0], bl[0], acc[mi][ni]);
                acc[mi][ni] = mfma16(ah[mi][1], bl[1], acc[mi][ni]);
                acc[mi][ni] = mfma16(al[mi][0], bh[0], acc[mi][ni]);
                acc[mi][ni] = mfma16(al[mi][1], bh[1], acc[mi][ni]);
            }
        }
        __syncthreads();
    }

    #pragma unroll
    for (int ni = 0; ni < 4; ++ni) {
        const int n = n0 + wn * 64 + ni * 16 + lm;
        const int hp = n >> 6, o = n & 63;
        const int h = hp / 3, p = hp - h * 3;
        if (p < 2) {
            uint16_t* __restrict__ dst = (p == 0) ? qf : kf;
            #pragma unroll
            for (int mi = 0; mi < 4; ++mi) {
                #pragma unroll
                for (int j = 0; j < 4; ++j) {
                    const int m = m0 + wm * 64 + mi * 16 + 4 * g + j;
                    const int b = m >> 11, s = m & 2047;
                    const size_t idx = ((size_t)(b * NH + h) * S_LEN + s) * DOUT + o;
                    const _Float16 hv = (_Float16)acc[mi][ni][j];  // RNE
                    dst[idx] = __builtin_bit_cast(uint16_t, hv);
                }
            }
        } else {
            #pragma unroll
            for (int mi = 0; mi < 4; ++mi) {
                const int m = m0 + wm * 64 + mi * 16 + 4 * g;  // 4 consecutive s
                const int b = m >> 11, s = m & 2047;
                union { _Float16 h[4]; uint2 u; } pk;
                pk.h[0] = (_Float16)acc[mi][ni][0];
                pk.h[1] = (_Float16)acc[mi][ni][1];
                pk.h[2] = (_Float16)acc[mi][ni][2];
                pk.h[3] = (_Float16)acc[mi][ni][3];
                *(uint2*)(vT + ((size_t)((b * NH + h) * DOUT + o)) * S_LEN + s) = pk.u;
            }
        }
    }
}

// ---------------------------------------------------------------------------
// Kernel 4: flash attention. R11 structure (fragment-major LDS dbuf, fp16
//   32x32 MFMA, in-register softmax, QK(kt+1)||softmax(kt)) but staging is
//   T14 REG-STAGING: coalesced global_load_dwordx4 -> 16 VGPRs -> ds_write
//   into the same fragment-major granules (replaces the lane-serial
//   global_load_lds DMA engine, the R11/R12 volume bottleneck).
//   Pipeline: tiles issued 2 ahead (sets alternate by tile parity); per iter:
//   compute(kt) -> barrier -> commit(kt+2) ds_writes -> issue(kt+4) ->
//   lgkmcnt(0) -> barrier.
// ---------------------------------------------------------------------------
__global__ __launch_bounds__(256, 2) void attn_fwd(
    const uint16_t* __restrict__ qf, const uint16_t* __restrict__ kf,
    const uint16_t* __restrict__ vT, uint16_t* __restrict__ oc)
{
    __shared__ __align__(16) char smem[32768];
    // kbuf0 @0, kbuf1 @8192, vbuf0 @16384, vbuf1 @24576
    char* __restrict__ vbufs = smem + 16384;

    const int bid = blockIdx.x;
    const int qt = (bid >> 3) & 15, bh = (bid & 7) + 8 * (bid >> 7);
    const int tid = threadIdx.x;
    const int l = tid & 63, wq = tid >> 6;
    const int L = l >> 5, lq = l & 31;
    const size_t base = (size_t)bh * (S_LEN * DOUT);

    // reg-staging geometry: thread t handles rows tr, tr+32 at 16B col tc;
    // coalesced global reads; fragment-major LDS granule
    //   g(r) = (r>>5)*256 + (tc/8)*32 + (r&31), dest byte = g*16.
    const int tr = tid >> 3, tc8 = (tid & 7) * 8;
    const uint16_t* __restrict__ kgb = kf + base + (size_t)tr * DOUT + tc8;
    const uint16_t* __restrict__ vgb = vT + base + (size_t)tr * S_LEN + tc8;
    const uint32_t wo16 = (uint32_t)(((tid & 7) * 32 + tr) * 16);

    // Q B-fragments (fp16): lane holds Q[q = qrow][d = dsub*16 + 8L + j]
    const int qrow = qt * 128 + wq * 32 + lq;
    const uint16_t* qp = qf + base + (size_t)qrow * DOUT;
    f16x8 qv[4];
    #pragma unroll
    for (int dsub = 0; dsub < 4; ++dsub)
        qv[dsub] = *(const f16x8*)(qp + dsub * 16 + L * 8);

    f32x16 Zv;
    #pragma unroll
    for (int r = 0; r < 16; ++r) Zv[r] = 0.f;
    f32x16 Oa[2] = {Zv, Zv};
    float m_run = -INFINITY, l_run = 0.f;

    uint4 stgA[4], stgB[4];
    auto issue = [&](int tk, uint4* stg) {
        const int s0 = (tk < 32) ? tk * 64 : 0;
        stg[0] = *(const uint4*)(kgb + (size_t)s0 * DOUT);
        stg[1] = *(const uint4*)(kgb + (size_t)(s0 + 32) * DOUT);
        stg[2] = *(const uint4*)(vgb + s0);
        stg[3] = *(const uint4*)(vgb + (size_t)32 * S_LEN + s0);
    };
    auto commit = [&](int tk, const uint4* stg) {
        char* __restrict__ kb = smem + (tk & 1) * 8192;
        char* __restrict__ vb = vbufs + (tk & 1) * 8192;
        *(uint4*)(kb + wo16)        = stg[0];
        *(uint4*)(kb + 4096 + wo16) = stg[1];
        *(uint4*)(vb + wo16)        = stg[2];
        *(uint4*)(vb + 4096 + wo16) = stg[3];
    };
    auto qk_step = [&](const char* kb2, f32x16* dst) {
        __builtin_amdgcn_s_setprio(1);
        #pragma unroll
        for (int ks = 0; ks < 2; ++ks) {
            f32x16 s = Zv;
            #pragma unroll
            for (int dsub = 0; dsub < 4; ++dsub) {
                const uint32_t off = (uint32_t)(((ks * 4 + dsub) << 10) + (l << 4));
                const f16x8 kfr = *(const f16x8*)(kb2 + off);
                s = mfma32h(kfr, qv[dsub], s);
            }
            dst[ks] = s;
        }
        __builtin_amdgcn_s_setprio(0);
    };

    // prologue: tiles 0,1 loaded+committed; tiles 2,3 issued (in flight)
    issue(0, stgA);
    issue(1, stgB);
    commit(0, stgA);           // compiler waits stgA values
    commit(1, stgB);
    issue(2, stgA);
    issue(3, stgB);
    asm volatile("s_waitcnt lgkmcnt(0)" ::: "memory");
    __builtin_amdgcn_s_barrier();
    __builtin_amdgcn_sched_barrier(0);

    f32x16 saA[2], saB[2];
    qk_step(smem, saA);        // QK(0) from kbuf0

    auto iter = [&](int kt, f32x16* sa, f32x16* sb, uint4* stg) {
        // [c] QK(kt+1) (MFMA) || softmax(kt) (VALU/TRANS)
        qk_step(smem + ((kt + 1) & 1) * 8192, sb);

        float mx[16];
        #pragma unroll
        for (int r = 0; r < 16; ++r) mx[r] = fmaxf(sa[0][r], sa[1][r]);
        #pragma unroll
        for (int st = 8; st >= 1; st >>= 1)
            #pragma unroll
            for (int r = 0; r < st; ++r) mx[r] = fmaxf(mx[r], mx[r + st]);
        float pmax = mx[0];
        pmax = fmaxf(pmax, __shfl_xor(pmax, 32));

        if (!__all(pmax - m_run <= 8.f)) {
            const float m_new = fmaxf(m_run, pmax);
            const float alpha = __builtin_amdgcn_exp2f(m_run - m_new);
            m_run = m_new;
            #pragma unroll
            for (int r = 0; r < 16; ++r) { Oa[0][r] *= alpha; Oa[1][r] *= alpha; }
            l_run *= alpha;
        }

        #pragma unroll
        for (int ks = 0; ks < 2; ++ks)
            #pragma unroll
            for (int r = 0; r < 16; ++r)
                sa[ks][r] = __builtin_amdgcn_exp2f(sa[ks][r] - m_run);

        float sm[16];
        #pragma unroll
        for (int r = 0; r < 16; ++r) sm[r] = sa[0][r] + sa[1][r];
        #pragma unroll
        for (int st = 8; st >= 1; st >>= 1)
            #pragma unroll
            for (int r = 0; r < st; ++r) sm[r] += sm[r + st];
        float lsum = sm[0];
        lsum += __shfl_xor(lsum, 32);
        l_run += lsum;

        // pack P (fp16) into PV B-fragments; permlane VDST = lo pack
        f16x8 pfrag[4];
        #pragma unroll
        for (int ks = 0; ks < 2; ++ks) {
            uint32_t a0 = cvt_pkrtz_f16(sa[ks][0], sa[ks][1]);
            uint32_t a1 = cvt_pkrtz_f16(sa[ks][2], sa[ks][3]);
            uint32_t a2 = cvt_pkrtz_f16(sa[ks][4], sa[ks][5]);
            uint32_t a3 = cvt_pkrtz_f16(sa[ks][6], sa[ks][7]);
            asm volatile("v_permlane32_swap_b32 %0, %1" : "+v"(a0), "+v"(a2));
            asm volatile("v_permlane32_swap_b32 %0, %1" : "+v"(a1), "+v"(a3));
            union { uint32_t w[4]; f16x8 v; } u;
            u.w[0] = a0; u.w[1] = a1; u.w[2] = a2; u.w[3] = a3;
            pfrag[2 * ks] = u.v;
            uint32_t b0 = cvt_pkrtz_f16(sa[ks][8],  sa[ks][9]);
            uint32_t b1 = cvt_pkrtz_f16(sa[ks][10], sa[ks][11]);
            uint32_t b2 = cvt_pkrtz_f16(sa[ks][12], sa[ks][13]);
            uint32_t b3 = cvt_pkrtz_f16(sa[ks][14], sa[ks][15]);
            asm volatile("v_permlane32_swap_b32 %0, %1" : "+v"(b0), "+v"(b2));
            asm volatile("v_permlane32_swap_b32 %0, %1" : "+v"(b1), "+v"(b3));
            union { uint32_t w[4]; f16x8 v; } u2;
            u2.w[0] = b0; u2.w[1] = b1; u2.w[2] = b2; u2.w[3] = b3;
            pfrag[2 * ks + 1] = u2.v;
        }

        // [d] PV(kt) from vbuf[kt&1]
        const char* __restrict__ vb = vbufs + (kt & 1) * 8192;
        __builtin_amdgcn_s_setprio(1);
        #pragma unroll
        for (int dh = 0; dh < 2; ++dh) {
            #pragma unroll
            for (int kc = 0; kc < 4; ++kc) {
                const uint32_t off = (uint32_t)(((dh * 4 + kc) << 10) + (l << 4));
                const f16x8 vv = *(const f16x8*)(vb + off);
                Oa[dh] = mfma32h(vv, pfrag[kc], Oa[dh]);
            }
        }
        __builtin_amdgcn_s_setprio(0);

        // [e] all waves done reading buf[kt&1] -> overwrite with tile kt+2
        __builtin_amdgcn_s_barrier();
        commit(kt + 2, stg);        // auto-vmcnt: values issued 2 iters ago
        issue(kt + 4, stg);         // reuse the drained set
        asm volatile("s_waitcnt lgkmcnt(0)" ::: "memory");
        __builtin_amdgcn_sched_barrier(0);
        __builtin_amdgcn_s_barrier();
    };

    for (int t = 0; t < 16; ++t) {
        iter(2 * t,     saA, saB, stgA);
        iter(2 * t + 1, saB, saA, stgB);
    }

    // epilogue: lane-local normalize; O^T -> oc[b][s][h*64+d] bf16, 8B packed
    const int b = bh >> 3, hh = bh & 7;
    const float li = 1.f / l_run;
    const int srow = qt * 128 + wq * 32 + lq;
    const size_t rbase = ((size_t)b * S_LEN + srow) * (NH * DOUT) + hh * DOUT;
    #pragma unroll
    for (int dh = 0; dh < 2; ++dh) {
        #pragma unroll
        for (int rq = 0; rq < 4; ++rq) {
            const int d0 = dh * 32 + rq * 8 + L * 4;
            uint2 val;
            val.x = cvt_pk_bf16(Oa[dh][rq * 4 + 0] * li, Oa[dh][rq * 4 + 1] * li);
            val.y = cvt_pk_bf16(Oa[dh][rq * 4 + 2] * li, Oa[dh][rq * 4 + 3] * li);
            *(uint2*)(oc + rbase + d0) = val;
        }
    }
}

// ---------------------------------------------------------------------------
// Kernel 5: output projection out = o_concat[8192x512] @ wo[512x64], fp32 out.
// ---------------------------------------------------------------------------
__global__ __launch_bounds__(256) void oproj(
    const uint16_t* __restrict__ oc, const uint16_t* __restrict__ woT,
    float* __restrict__ out)
{
    const int mt = blockIdx.x;
    const int tid = threadIdx.x;
    const int l = tid & 63, w = tid >> 6;
    const int g = l >> 4, lm = l & 15;
    const int m0 = mt * 64 + w * 16;
    const f32x4 Z = {0.f, 0.f, 0.f, 0.f};
    f32x4 acc[4] = {Z, Z, Z, Z};
    const uint16_t* __restrict__ arow = oc + (size_t)(m0 + lm) * (NH * DOUT);
    for (int kc = 0; kc < 16; ++kc) {
        const bf16x8 a = *(const bf16x8*)(arow + kc * 32 + g * 8);
        #pragma unroll
        for (int nt = 0; nt < 4; ++nt) {
            const bf16x8 bfr = *(const bf16x8*)(woT + (size_t)(nt * 16 + lm) * (NH * DOUT) + kc * 32 + g * 8);
            acc[nt] = mfma16(a, bfr, acc[nt]);
        }
    }
    #pragma unroll
    for (int nt = 0; nt < 4; ++nt)
        #pragma unroll
        for (int j = 0; j < 4; ++j)
            out[(size_t)(m0 + 4 * g + j) * DOUT + nt * 16 + lm] = acc[nt][j];
}

// ---------------------------------------------------------------------------
extern "C" void kernel_launch(void* const* d_in, const int* in_sizes, int n_in,
                              void* d_out, int out_size, void* d_ws, size_t ws_size,
                              hipStream_t stream) {
    const float* x  = (const float*)d_in[0];
    const float* w  = (const float*)d_in[1];
    const float* wo = (const float*)d_in[2];
    float* out = (float*)d_out;

    char* ws = (char*)d_ws;
    uint16_t* qf   = (uint16_t*)(ws);              // [B*H][S][64] fp16, 8 MB
    uint16_t* kf   = (uint16_t*)(ws + 8388608);    // fp16, 8 MB
    uint16_t* vT   = (uint16_t*)(ws + 16777216);   // [B*H][64][S] fp16, 8 MB
    uint16_t* xhi  = (uint16_t*)(ws + 25165824);   // bf16, 8 MB (-> oc)
    uint16_t* xlo  = (uint16_t*)(ws + 33554432);   // bf16, 8 MB
    uint16_t* whiT = (uint16_t*)(ws + 41943040);   // [1536][512] bf16
    uint16_t* wloT = (uint16_t*)(ws + 43515904);
    uint16_t* woT  = (uint16_t*)(ws + 45088768);   // 65536 B
    // oc aliases xhi (dead after gemm_qkv; split_x rewrites it every call).
    uint16_t* oc   = xhi;

    hipLaunchKernelGGL(prep_w, dim3(200), dim3(256), 0, stream, w, wo, whiT, wloT, woT);
    hipLaunchKernelGGL(split_x, dim3(2048), dim3(256), 0, stream, x, xhi, xlo);
    hipLaunchKernelGGL(gemm_qkv, dim3(768), dim3(256), 0, stream,
                       xhi, xlo, whiT, wloT, qf, kf, vT);
    hipLaunchKernelGGL(attn_fwd, dim3(512), dim3(256), 0, stream,
                       qf, kf, vT, oc);
    hipLaunchKernelGGL(oproj, dim3(128), dim3(256), 0, stream, oc, woT, out);
}

// Round 15
// 115.572 us; speedup vs baseline: 1.6100x; 1.3360x over previous
//
#include <hip/hip_runtime.h>
#include <cstdint>
#include <cstddef>

#define S_LEN 2048
#define DIN   512
#define DOUT  64
#define NB    4
#define NH    8

typedef __attribute__((ext_vector_type(8))) short bf16x8;
typedef __attribute__((ext_vector_type(8))) _Float16 f16x8;
typedef __attribute__((ext_vector_type(4))) float f32x4;
typedef __attribute__((ext_vector_type(16))) float f32x16;

static __device__ __forceinline__ f32x4 mfma16(bf16x8 a, bf16x8 b, f32x4 c) {
    return __builtin_amdgcn_mfma_f32_16x16x32_bf16(a, b, c, 0, 0, 0);
}
static __device__ __forceinline__ f32x16 mfma32h(f16x8 a, f16x8 b, f32x16 c) {
    return __builtin_amdgcn_mfma_f32_32x32x16_f16(a, b, c, 0, 0, 0);
}

static __device__ __forceinline__ uint16_t f2bf(float x) {
    uint32_t u = __builtin_bit_cast(uint32_t, x);
    u += 0x7fffu + ((u >> 16) & 1u);
    return (uint16_t)(u >> 16);
}
static __device__ __forceinline__ float bf2f(uint16_t h) {
    uint32_t u = ((uint32_t)h) << 16;
    return __builtin_bit_cast(float, u);
}
static __device__ __forceinline__ uint32_t cvt_pk_bf16(float lo, float hi) {
    uint32_t r;
    asm("v_cvt_pk_bf16_f32 %0, %1, %2" : "=v"(r) : "v"(lo), "v"(hi));
    return r;
}
static __device__ __forceinline__ uint32_t cvt_pkrtz_f16(float lo, float hi) {
    return __builtin_bit_cast(uint32_t, __builtin_amdgcn_cvt_pkrtz(lo, hi));
}

// ---------------------------------------------------------------------------
// Kernel 1: weight prep via LDS transpose (coalesced both sides).
// ---------------------------------------------------------------------------
__global__ __launch_bounds__(256) void prep_w(
    const float* __restrict__ w, const float* __restrict__ wo,
    uint16_t* __restrict__ whiT, uint16_t* __restrict__ wloT,
    uint16_t* __restrict__ woT)
{
    __shared__ float tile[64][65];
    const int blk = blockIdx.x;
    const int t = threadIdx.x;
    const int tq = t >> 6, tr = t & 63;

    if (blk < 192) {
        const int hp = blk >> 3, i0 = (blk & 7) * 64;
        const int p = hp % 3;
        const float s = (p == 0) ? 0.18033688011112042f : 1.0f; // 0.125*log2(e)
        const float* __restrict__ src = w + (size_t)hp * (DIN * DOUT);
        #pragma unroll
        for (int r = 0; r < 16; ++r) {
            const int ir = r * 4 + tq;
            tile[ir][tr] = src[(size_t)(i0 + ir) * DOUT + tr];
        }
        __syncthreads();
        uint16_t* __restrict__ dh = whiT + (size_t)hp * (DOUT * DIN);
        uint16_t* __restrict__ dl = wloT + (size_t)hp * (DOUT * DIN);
        #pragma unroll
        for (int r = 0; r < 16; ++r) {
            const int o = r * 4 + tq;
            const float v = tile[tr][o] * s;
            const uint16_t hi = f2bf(v);
            dh[(size_t)o * DIN + i0 + tr] = hi;
            dl[(size_t)o * DIN + i0 + tr] = f2bf(v - bf2f(hi));
        }
    } else {
        const int i0 = (blk - 192) * 64;
        #pragma unroll
        for (int r = 0; r < 16; ++r) {
            const int ir = r * 4 + tq;
            tile[ir][tr] = wo[(size_t)(i0 + ir) * DOUT + tr];
        }
        __syncthreads();
        #pragma unroll
        for (int r = 0; r < 16; ++r) {
            const int o = r * 4 + tq;
            woT[(size_t)o * DIN + i0 + tr] = f2bf(tile[tr][o]);
        }
    }
}

// ---------------------------------------------------------------------------
// Kernel 2: split x [8192][512] fp32 -> xhi/xlo bf16 (vectorized, one pass).
// ---------------------------------------------------------------------------
__global__ __launch_bounds__(256) void split_x(
    const float* __restrict__ x, uint16_t* __restrict__ xhi, uint16_t* __restrict__ xlo)
{
    const size_t idx = ((size_t)blockIdx.x * 256 + threadIdx.x) * 8;
    const float4 a = *(const float4*)(x + idx);
    const float4 b = *(const float4*)(x + idx + 4);
    const float xv[8] = {a.x, a.y, a.z, a.w, b.x, b.y, b.z, b.w};
    union { uint16_t u[8]; uint4 v; } H, L;
    #pragma unroll
    for (int j = 0; j < 8; ++j) {
        const uint16_t hi = f2bf(xv[j]);
        H.u[j] = hi;
        L.u[j] = f2bf(xv[j] - bf2f(hi));
    }
    *(uint4*)(xhi + idx) = H.v;
    *(uint4*)(xlo + idx) = L.v;
}

// ---------------------------------------------------------------------------
// Kernel 3: QKV projection GEMM (fused 3-term, reg-staged).
// Outputs: q fp16 [bh][s][64]; K,V in FRAGMENT-MAJOR tile layout:
//   kfm/vfm[bh][tile=s>>6][512 granules x 8 fp16]  (8 KB per tile)
//   K granule for (srow,o): g=((srow>>5)*4+(o>>4))*64+((o>>3)&1)*32+(srow&31)
//   V granule for (d,sc):   g=((d>>5)*4+(sc>>4))*64+((sc>>3)&1)*32+(d&31)
// so attn can stage tiles with a LINEAR copy (coalesced + conflict-free).
// ---------------------------------------------------------------------------
__global__ __launch_bounds__(256, 2) void gemm_qkv(
    const uint16_t* __restrict__ xhi, const uint16_t* __restrict__ xlo,
    const uint16_t* __restrict__ whiT, const uint16_t* __restrict__ wloT,
    uint16_t* __restrict__ qf, uint16_t* __restrict__ kfm,
    uint16_t* __restrict__ vfm)
{
    __shared__ __align__(16) uint16_t lds[4 * 128 * 64];   // 64 KB: ah|al|bh|bl

    const int bid = blockIdx.x;
    const int xcd = bid & 7, wi = bid >> 3;
    const int mt = xcd * 8 + wi / 12, nt = wi % 12;
    const int m0 = mt * 128, n0 = nt * 128;
    const int tid = threadIdx.x;
    const int l = tid & 63, w = tid >> 6;
    const int g = l >> 4, lm = l & 15;
    const int wm = w >> 1, wn = w & 1;

    const f32x4 Z = {0.f, 0.f, 0.f, 0.f};
    f32x4 acc[4][4];
    #pragma unroll
    for (int a = 0; a < 4; ++a)
        #pragma unroll
        for (int b = 0; b < 4; ++b) acc[a][b] = Z;

    int srow[4], scol[4];
    #pragma unroll
    for (int i = 0; i < 4; ++i) {
        const int c = i * 256 + tid;
        srow[i] = c >> 3;
        scol[i] = ((c & 7) * 8) ^ ((srow[i] & 7) << 3);
    }

    for (int kt = 0; kt < 8; ++kt) {
        const int k0 = kt * 64;
        uint4 stg[16];
        #pragma unroll
        for (int i = 0; i < 4; ++i) {
            const size_t aoff = (size_t)(m0 + srow[i]) * DIN + k0 + scol[i];
            const size_t boff = (size_t)(n0 + srow[i]) * DIN + k0 + scol[i];
            stg[i * 4 + 0] = *(const uint4*)(xhi  + aoff);
            stg[i * 4 + 1] = *(const uint4*)(xlo  + aoff);
            stg[i * 4 + 2] = *(const uint4*)(whiT + boff);
            stg[i * 4 + 3] = *(const uint4*)(wloT + boff);
        }
        #pragma unroll
        for (int i = 0; i < 4; ++i) {
            const int c8 = (i * 256 + tid) * 8;
            *(uint4*)&lds[c8]                 = stg[i * 4 + 0];
            *(uint4*)&lds[128 * 64 + c8]      = stg[i * 4 + 1];
            *(uint4*)&lds[2 * 128 * 64 + c8]  = stg[i * 4 + 2];
            *(uint4*)&lds[3 * 128 * 64 + c8]  = stg[i * 4 + 3];
        }
        __syncthreads();

        bf16x8 ah[4][2], al[4][2];
        #pragma unroll
        for (int mi = 0; mi < 4; ++mi) {
            const int r = wm * 64 + mi * 16 + lm;
            const int rb = r * 128;
            #pragma unroll
            for (int kk = 0; kk < 2; ++kk) {
                const int cb = (kk * 64 + g * 16) ^ ((r & 7) << 4);
                ah[mi][kk] = *(const bf16x8*)((const char*)lds + rb + cb);
                al[mi][kk] = *(const bf16x8*)((const char*)lds + 16384 + rb + cb);
            }
        }
        #pragma unroll
        for (int ni = 0; ni < 4; ++ni) {
            const int r = wn * 64 + ni * 16 + lm;
            const int rb = r * 128;
            bf16x8 bh[2], bl[2];
            #pragma unroll
            for (int kk = 0; kk < 2; ++kk) {
                const int cb = (kk * 64 + g * 16) ^ ((r & 7) << 4);
                bh[kk] = *(const bf16x8*)((const char*)lds + 32768 + rb + cb);
                bl[kk] = *(const bf16x8*)((const char*)lds + 49152 + rb + cb);
            }
            #pragma unroll
            for (int mi = 0; mi < 4; ++mi) {
                acc[mi][ni] = mfma16(ah[mi][0], bh[0], acc[mi][ni]);
                acc[mi][ni] = mfma16(ah[mi][1], bh[1], acc[mi][ni]);
                acc[mi][ni] = mfma16(ah[mi][0], bl[0], acc[mi][ni]);
                acc[mi][ni] = mfma16(ah[mi][1], bl[1], acc[mi][ni]);
                acc[mi][ni] = mfma16(al[mi][0], bh[0], acc[mi][ni]);
                acc[mi][ni] = mfma16(al[mi][1], bh[1], acc[mi][ni]);
            }
        }
        __syncthreads();
    }

    #pragma unroll
    for (int ni = 0; ni < 4; ++ni) {
        const int n = n0 + wn * 64 + ni * 16 + lm;
        const int hp = n >> 6, o = n & 63;
        const int h = hp / 3, p = hp - h * 3;
        if (p == 0) {
            #pragma unroll
            for (int mi = 0; mi < 4; ++mi) {
                #pragma unroll
                for (int j = 0; j < 4; ++j) {
                    const int m = m0 + wm * 64 + mi * 16 + 4 * g + j;
                    const int b = m >> 11, s = m & 2047;
                    const size_t idx = ((size_t)(b * NH + h) * S_LEN + s) * DOUT + o;
                    const _Float16 hv = (_Float16)acc[mi][ni][j];  // RNE
                    qf[idx] = __builtin_bit_cast(uint16_t, hv);
                }
            }
        } else if (p == 1) {
            // K fragment-major scatter (4 consecutive srow -> 4 granules, +8elem apart)
            #pragma unroll
            for (int mi = 0; mi < 4; ++mi) {
                const int m = m0 + wm * 64 + mi * 16 + 4 * g;
                const int b = m >> 11, s = m & 2047;
                const int tile = s >> 6, sr = s & 63;
                const int gam = ((sr >> 5) * 4 + (o >> 4)) * 64 + ((o >> 3) & 1) * 32 + (sr & 31);
                uint16_t* __restrict__ dst =
                    kfm + ((size_t)((b * NH + h) * 32 + tile)) * 4096 + gam * 8 + (o & 7);
                #pragma unroll
                for (int j = 0; j < 4; ++j) {
                    const _Float16 hv = (_Float16)acc[mi][ni][j];
                    dst[j * 8] = __builtin_bit_cast(uint16_t, hv);  // granule+1 = +8 elem
                }
            }
        } else {
            // V fragment-major: thread has d=o fixed, 4 consecutive sc -> one 8B store
            #pragma unroll
            for (int mi = 0; mi < 4; ++mi) {
                const int m = m0 + wm * 64 + mi * 16 + 4 * g;
                const int b = m >> 11, s = m & 2047;
                const int tile = s >> 6, sc = s & 63;
                const int gam = ((o >> 5) * 4 + (sc >> 4)) * 64 + ((sc >> 3) & 1) * 32 + (o & 31);
                union { _Float16 h[4]; uint2 u; } pk;
                pk.h[0] = (_Float16)acc[mi][ni][0];
                pk.h[1] = (_Float16)acc[mi][ni][1];
                pk.h[2] = (_Float16)acc[mi][ni][2];
                pk.h[3] = (_Float16)acc[mi][ni][3];
                *(uint2*)(vfm + ((size_t)((b * NH + h) * 32 + tile)) * 4096
                              + gam * 8 + (sc & 7)) = pk.u;
            }
        }
    }
}

// ---------------------------------------------------------------------------
// Kernel 4: flash attention. R11 pipeline (fragment-major LDS dbuf, fp16
//   32x32 MFMA, in-register softmax, QK(kt+1)||softmax(kt)), staging =
//   LINEAR reg-copy from fragment-major global tiles: thread t copies bytes
//   t*16 and (t+256)*16 of the 8KB tile (coalesced loads, conflict-free
//   consecutive ds_writes). Staging regs are NAMED uint4 (no arrays ->
//   no scratch, rule #20). Tiles issued 2 ahead, sets alternate by parity.
// ---------------------------------------------------------------------------
__global__ __launch_bounds__(256, 2) void attn_fwd(
    const uint16_t* __restrict__ qf, const uint16_t* __restrict__ kfm,
    const uint16_t* __restrict__ vfm, uint16_t* __restrict__ oc)
{
    __shared__ __align__(16) char smem[32768];
    // kbuf0 @0, kbuf1 @8192, vbuf0 @16384, vbuf1 @24576
    char* __restrict__ vbufs = smem + 16384;

    const int bid = blockIdx.x;
    const int qt = (bid >> 3) & 15, bh = (bid & 7) + 8 * (bid >> 7);
    const int tid = threadIdx.x;
    const int l = tid & 63, wq = tid >> 6;
    const int L = l >> 5, lq = l & 31;
    const size_t base = (size_t)bh * (S_LEN * DOUT);

    const uint16_t* __restrict__ ktb = kfm + (size_t)bh * 131072;  // 32 tiles * 4096
    const uint16_t* __restrict__ vtb = vfm + (size_t)bh * 131072;
    const uint32_t t16 = (uint32_t)tid * 16;

    // Q B-fragments (fp16): lane holds Q[q = qrow][d = dsub*16 + 8L + j]
    const int qrow = qt * 128 + wq * 32 + lq;
    const uint16_t* qp = qf + base + (size_t)qrow * DOUT;
    f16x8 qv[4];
    #pragma unroll
    for (int dsub = 0; dsub < 4; ++dsub)
        qv[dsub] = *(const f16x8*)(qp + dsub * 16 + L * 8);

    f32x16 Zv;
    #pragma unroll
    for (int r = 0; r < 16; ++r) Zv[r] = 0.f;
    f32x16 Oa[2] = {Zv, Zv};
    float m_run = -INFINITY, l_run = 0.f;

    // named staging regs (2 sets x {K lo/hi half, V lo/hi half})
    uint4 kA0, kA1, vA0, vA1, kB0, kB1, vB0, vB1;

    auto qk_step = [&](const char* kb2, f32x16* dst) {
        __builtin_amdgcn_s_setprio(1);
        #pragma unroll
        for (int ks = 0; ks < 2; ++ks) {
            f32x16 s = Zv;
            #pragma unroll
            for (int dsub = 0; dsub < 4; ++dsub) {
                const uint32_t off = (uint32_t)(((ks * 4 + dsub) << 10) + (l << 4));
                const f16x8 kfr = *(const f16x8*)(kb2 + off);
                s = mfma32h(kfr, qv[dsub], s);
            }
            dst[ks] = s;
        }
        __builtin_amdgcn_s_setprio(0);
    };

    // prologue: tiles 0,1 loaded+committed; tiles 2,3 issued (in flight)
    kA0 = *(const uint4*)(ktb + (size_t)tid * 8);
    kA1 = *(const uint4*)(ktb + 2048 + (size_t)tid * 8);
    vA0 = *(const uint4*)(vtb + (size_t)tid * 8);
    vA1 = *(const uint4*)(vtb + 2048 + (size_t)tid * 8);
    kB0 = *(const uint4*)(ktb + 4096 + (size_t)tid * 8);
    kB1 = *(const uint4*)(ktb + 6144 + (size_t)tid * 8);
    vB0 = *(const uint4*)(vtb + 4096 + (size_t)tid * 8);
    vB1 = *(const uint4*)(vtb + 6144 + (size_t)tid * 8);
    *(uint4*)(smem + t16)          = kA0;
    *(uint4*)(smem + 4096 + t16)   = kA1;
    *(uint4*)(vbufs + t16)         = vA0;
    *(uint4*)(vbufs + 4096 + t16)  = vA1;
    *(uint4*)(smem + 8192 + t16)   = kB0;
    *(uint4*)(smem + 12288 + t16)  = kB1;
    *(uint4*)(vbufs + 8192 + t16)  = vB0;
    *(uint4*)(vbufs + 12288 + t16) = vB1;
    {
        const size_t o2 = (size_t)2 * 4096 + tid * 8, o3 = (size_t)3 * 4096 + tid * 8;
        kA0 = *(const uint4*)(ktb + o2); kA1 = *(const uint4*)(ktb + o2 + 2048);
        vA0 = *(const uint4*)(vtb + o2); vA1 = *(const uint4*)(vtb + o2 + 2048);
        kB0 = *(const uint4*)(ktb + o3); kB1 = *(const uint4*)(ktb + o3 + 2048);
        vB0 = *(const uint4*)(vtb + o3); vB1 = *(const uint4*)(vtb + o3 + 2048);
    }
    asm volatile("s_waitcnt lgkmcnt(0)" ::: "memory");
    __builtin_amdgcn_s_barrier();
    __builtin_amdgcn_sched_barrier(0);

    f32x16 saA[2], saB[2];
    qk_step(smem, saA);        // QK(0) from kbuf0

    auto iter = [&](int kt, f32x16* sa, f32x16* sb,
                    uint4& k0, uint4& k1, uint4& v0, uint4& v1) {
        // [c] QK(kt+1) (MFMA) || softmax(kt) (VALU/TRANS)
        qk_step(smem + ((kt + 1) & 1) * 8192, sb);

        float mx[16];
        #pragma unroll
        for (int r = 0; r < 16; ++r) mx[r] = fmaxf(sa[0][r], sa[1][r]);
        #pragma unroll
        for (int st = 8; st >= 1; st >>= 1)
            #pragma unroll
            for (int r = 0; r < st; ++r) mx[r] = fmaxf(mx[r], mx[r + st]);
        float pmax = mx[0];
        pmax = fmaxf(pmax, __shfl_xor(pmax, 32));

        if (!__all(pmax - m_run <= 8.f)) {
            const float m_new = fmaxf(m_run, pmax);
            const float alpha = __builtin_amdgcn_exp2f(m_run - m_new);
            m_run = m_new;
            #pragma unroll
            for (int r = 0; r < 16; ++r) { Oa[0][r] *= alpha; Oa[1][r] *= alpha; }
            l_run *= alpha;
        }

        #pragma unroll
        for (int ks = 0; ks < 2; ++ks)
            #pragma unroll
            for (int r = 0; r < 16; ++r)
                sa[ks][r] = __builtin_amdgcn_exp2f(sa[ks][r] - m_run);

        float sm[16];
        #pragma unroll
        for (int r = 0; r < 16; ++r) sm[r] = sa[0][r] + sa[1][r];
        #pragma unroll
        for (int st = 8; st >= 1; st >>= 1)
            #pragma unroll
            for (int r = 0; r < st; ++r) sm[r] += sm[r + st];
        float lsum = sm[0];
        lsum += __shfl_xor(lsum, 32);
        l_run += lsum;

        // pack P (fp16) into PV B-fragments; permlane VDST = lo pack
        f16x8 pfrag[4];
        #pragma unroll
        for (int ks = 0; ks < 2; ++ks) {
            uint32_t a0 = cvt_pkrtz_f16(sa[ks][0], sa[ks][1]);
            uint32_t a1 = cvt_pkrtz_f16(sa[ks][2], sa[ks][3]);
            uint32_t a2 = cvt_pkrtz_f16(sa[ks][4], sa[ks][5]);
            uint32_t a3 = cvt_pkrtz_f16(sa[ks][6], sa[ks][7]);
            asm volatile("v_permlane32_swap_b32 %0, %1" : "+v"(a0), "+v"(a2));
            asm volatile("v_permlane32_swap_b32 %0, %1" : "+v"(a1), "+v"(a3));
            union { uint32_t w[4]; f16x8 v; } u;
            u.w[0] = a0; u.w[1] = a1; u.w[2] = a2; u.w[3] = a3;
            pfrag[2 * ks] = u.v;
            uint32_t b0 = cvt_pkrtz_f16(sa[ks][8],  sa[ks][9]);
            uint32_t b1 = cvt_pkrtz_f16(sa[ks][10], sa[ks][11]);
            uint32_t b2 = cvt_pkrtz_f16(sa[ks][12], sa[ks][13]);
            uint32_t b3 = cvt_pkrtz_f16(sa[ks][14], sa[ks][15]);
            asm volatile("v_permlane32_swap_b32 %0, %1" : "+v"(b0), "+v"(b2));
            asm volatile("v_permlane32_swap_b32 %0, %1" : "+v"(b1), "+v"(b3));
            union { uint32_t w[4]; f16x8 v; } u2;
            u2.w[0] = b0; u2.w[1] = b1; u2.w[2] = b2; u2.w[3] = b3;
            pfrag[2 * ks + 1] = u2.v;
        }

        // [d] PV(kt) from vbuf[kt&1]
        const char* __restrict__ vb = vbufs + (kt & 1) * 8192;
        __builtin_amdgcn_s_setprio(1);
        #pragma unroll
        for (int dh = 0; dh < 2; ++dh) {
            #pragma unroll
            for (int kc = 0; kc < 4; ++kc) {
                const uint32_t off = (uint32_t)(((dh * 4 + kc) << 10) + (l << 4));
                const f16x8 vv = *(const f16x8*)(vb + off);
                Oa[dh] = mfma32h(vv, pfrag[kc], Oa[dh]);
            }
        }
        __builtin_amdgcn_s_setprio(0);

        // [e] all waves done with buf[kt&1] -> commit tile kt+2, issue kt+4
        __builtin_amdgcn_s_barrier();
        {
            char* __restrict__ kb = smem + (kt & 1) * 8192;
            char* __restrict__ vbw = vbufs + (kt & 1) * 8192;
            *(uint4*)(kb + t16)         = k0;
            *(uint4*)(kb + 4096 + t16)  = k1;
            *(uint4*)(vbw + t16)        = v0;
            *(uint4*)(vbw + 4096 + t16) = v1;
            const int tk = (kt + 4 < 32) ? kt + 4 : 0;
            const size_t toff = (size_t)tk * 4096 + tid * 8;
            k0 = *(const uint4*)(ktb + toff);
            k1 = *(const uint4*)(ktb + toff + 2048);
            v0 = *(const uint4*)(vtb + toff);
            v1 = *(const uint4*)(vtb + toff + 2048);
        }
        asm volatile("s_waitcnt lgkmcnt(0)" ::: "memory");
        __builtin_amdgcn_sched_barrier(0);
        __builtin_amdgcn_s_barrier();
    };

    for (int t = 0; t < 16; ++t) {
        iter(2 * t,     saA, saB, kA0, kA1, vA0, vA1);
        iter(2 * t + 1, saB, saA, kB0, kB1, vB0, vB1);
    }

    // epilogue: lane-local normalize; O^T -> oc[b][s][h*64+d] bf16, 8B packed
    const int b = bh >> 3, hh = bh & 7;
    const float li = 1.f / l_run;
    const int srow = qt * 128 + wq * 32 + lq;
    const size_t rbase = ((size_t)b * S_LEN + srow) * (NH * DOUT) + hh * DOUT;
    #pragma unroll
    for (int dh = 0; dh < 2; ++dh) {
        #pragma unroll
        for (int rq = 0; rq < 4; ++rq) {
            const int d0 = dh * 32 + rq * 8 + L * 4;
            uint2 val;
            val.x = cvt_pk_bf16(Oa[dh][rq * 4 + 0] * li, Oa[dh][rq * 4 + 1] * li);
            val.y = cvt_pk_bf16(Oa[dh][rq * 4 + 2] * li, Oa[dh][rq * 4 + 3] * li);
            *(uint2*)(oc + rbase + d0) = val;
        }
    }
}

// ---------------------------------------------------------------------------
// Kernel 5: output projection out = o_concat[8192x512] @ wo[512x64], fp32 out.
// ---------------------------------------------------------------------------
__global__ __launch_bounds__(256) void oproj(
    const uint16_t* __restrict__ oc, const uint16_t* __restrict__ woT,
    float* __restrict__ out)
{
    const int mt = blockIdx.x;
    const int tid = threadIdx.x;
    const int l = tid & 63, w = tid >> 6;
    const int g = l >> 4, lm = l & 15;
    const int m0 = mt * 64 + w * 16;
    const f32x4 Z = {0.f, 0.f, 0.f, 0.f};
    f32x4 acc[4] = {Z, Z, Z, Z};
    const uint16_t* __restrict__ arow = oc + (size_t)(m0 + lm) * (NH * DOUT);
    for (int kc = 0; kc < 16; ++kc) {
        const bf16x8 a = *(const bf16x8*)(arow + kc * 32 + g * 8);
        #pragma unroll
        for (int nt = 0; nt < 4; ++nt) {
            const bf16x8 bfr = *(const bf16x8*)(woT + (size_t)(nt * 16 + lm) * (NH * DOUT) + kc * 32 + g * 8);
            acc[nt] = mfma16(a, bfr, acc[nt]);
        }
    }
    #pragma unroll
    for (int nt = 0; nt < 4; ++nt)
        #pragma unroll
        for (int j = 0; j < 4; ++j)
            out[(size_t)(m0 + 4 * g + j) * DOUT + nt * 16 + lm] = acc[nt][j];
}

// ---------------------------------------------------------------------------
extern "C" void kernel_launch(void* const* d_in, const int* in_sizes, int n_in,
                              void* d_out, int out_size, void* d_ws, size_t ws_size,
                              hipStream_t stream) {
    const float* x  = (const float*)d_in[0];
    const float* w  = (const float*)d_in[1];
    const float* wo = (const float*)d_in[2];
    float* out = (float*)d_out;

    char* ws = (char*)d_ws;
    uint16_t* qf   = (uint16_t*)(ws);              // [B*H][S][64] fp16, 8 MB
    uint16_t* kfm  = (uint16_t*)(ws + 8388608);    // fragment-major K, 8 MB
    uint16_t* vfm  = (uint16_t*)(ws + 16777216);   // fragment-major V, 8 MB
    uint16_t* xhi  = (uint16_t*)(ws + 25165824);   // bf16, 8 MB (-> oc)
    uint16_t* xlo  = (uint16_t*)(ws + 33554432);   // bf16, 8 MB
    uint16_t* whiT = (uint16_t*)(ws + 41943040);   // [1536][512] bf16
    uint16_t* wloT = (uint16_t*)(ws + 43515904);
    uint16_t* woT  = (uint16_t*)(ws + 45088768);   // 65536 B
    // oc aliases xhi (dead after gemm_qkv; split_x rewrites it every call).
    uint16_t* oc   = xhi;

    hipLaunchKernelGGL(prep_w, dim3(200), dim3(256), 0, stream, w, wo, whiT, wloT, woT);
    hipLaunchKernelGGL(split_x, dim3(2048), dim3(256), 0, stream, x, xhi, xlo);
    hipLaunchKernelGGL(gemm_qkv, dim3(768), dim3(256), 0, stream,
                       xhi, xlo, whiT, wloT, qf, kfm, vfm);
    hipLaunchKernelGGL(attn_fwd, dim3(512), dim3(256), 0, stream,
                       qf, kfm, vfm, oc);
    hipLaunchKernelGGL(oproj, dim3(128), dim3(256), 0, stream, oc, woT, out);
}